// Round 1
// baseline (164.108 us; speedup 1.0000x reference)
//
#include <hip/hip_runtime.h>

// Problem constants (fixed by setup_inputs)
#define B_    8
#define C_    256
#define H_    100
#define W_    152
#define K_    128
#define PH_   7
#define PW_   7
#define GH_   14
#define GW_   14
#define NSAMP 196      // GH_*GW_
#define CSPLIT 4
#define CPB   (C_ / CSPLIT)   // 64 channels per block
#define ELEMS (CPB * PH_ * PW_)  // 3136 outputs per block

__global__ __launch_bounds__(256) void roi_align_kernel(
    const float* __restrict__ feat,
    const float* __restrict__ rois,
    const int*   __restrict__ stride_p,
    float*       __restrict__ out)
{
    __shared__ int   s_off[NSAMP][4];
    __shared__ float s_w[NSAMP][4];

    const int blk   = blockIdx.x;
    const int n     = blk >> 2;              // ROI index 0..1023 (CSPLIT=4)
    const int cbase = (blk & 3) * CPB;
    const int b     = n / K_;

    const int t = threadIdx.x;

    // ---- per-ROI sample metadata into LDS (threads 0..195) ----
    if (t < NSAMP) {
        const float scale = 1.0f / (float)(*stride_p);
        const float* box = rois + n * 4;
        const float x1 = box[0], y1 = box[1], x2 = box[2], y2 = box[3];
        const float start_w = x1 * scale - 0.5f;
        const float start_h = y1 * scale - 0.5f;
        const float bin_w = (x2 - x1) * scale * (1.0f / PW_);
        const float bin_h = (y2 - y1) * scale * (1.0f / PH_);

        const int gh = t / GW_;
        const int gw = t - gh * GW_;
        const float y = start_h + ((float)gh + 0.5f) * 0.5f * bin_h;
        const float x = start_w + ((float)gw + 0.5f) * 0.5f * bin_w;

        const bool valid = (y >= -1.0f) && (y <= (float)H_) &&
                           (x >= -1.0f) && (x <= (float)W_);

        float yc = fminf(fmaxf(y, 0.0f), (float)(H_ - 1));
        float xc = fminf(fmaxf(x, 0.0f), (float)(W_ - 1));
        const float y0f = floorf(yc);
        const float x0f = floorf(xc);
        const float ly = yc - y0f, lx = xc - x0f;
        const float hy = 1.0f - ly, hx = 1.0f - lx;
        const int y0 = (int)y0f;
        const int x0 = (int)x0f;
        const int y1i = min(y0 + 1, H_ - 1);
        const int x1i = min(x0 + 1, W_ - 1);

        const float m = valid ? 0.25f : 0.0f;   // fold the s*s mean in

        s_off[t][0] = y0  * W_ + x0;
        s_off[t][1] = y0  * W_ + x1i;
        s_off[t][2] = y1i * W_ + x0;
        s_off[t][3] = y1i * W_ + x1i;
        s_w[t][0] = hy * hx * m;
        s_w[t][1] = hy * lx * m;
        s_w[t][2] = ly * hx * m;
        s_w[t][3] = ly * lx * m;
    }
    __syncthreads();

    const float* fb = feat + (size_t)b * C_ * (H_ * W_);
    float*       ob = out  + ((size_t)n * C_ + cbase) * (PH_ * PW_);

    for (int e = t; e < ELEMS; e += 256) {
        const int c   = e / 49;
        const int bin = e - c * 49;
        const int ph  = bin / 7;
        const int pw  = bin - ph * 7;
        const float* fp = fb + (size_t)(cbase + c) * (H_ * W_);

        float acc = 0.0f;
        #pragma unroll
        for (int sy = 0; sy < 2; ++sy) {
            #pragma unroll
            for (int sx = 0; sx < 2; ++sx) {
                const int si = (ph * 2 + sy) * GW_ + (pw * 2 + sx);
                acc += s_w[si][0] * fp[s_off[si][0]]
                     + s_w[si][1] * fp[s_off[si][1]]
                     + s_w[si][2] * fp[s_off[si][2]]
                     + s_w[si][3] * fp[s_off[si][3]];
            }
        }
        ob[e] = acc;
    }
}

extern "C" void kernel_launch(void* const* d_in, const int* in_sizes, int n_in,
                              void* d_out, int out_size, void* d_ws, size_t ws_size,
                              hipStream_t stream) {
    (void)in_sizes; (void)n_in; (void)out_size; (void)d_ws; (void)ws_size;
    const float* feat     = (const float*)d_in[0];
    const float* rois     = (const float*)d_in[1];
    const int*   stride_p = (const int*)  d_in[2];
    float*       out      = (float*)d_out;

    const int nblocks = B_ * K_ * CSPLIT;   // 1024 ROIs * 4 = 4096
    roi_align_kernel<<<nblocks, 256, 0, stream>>>(feat, rois, stride_p, out);
}

// Round 2
// 113.297 us; speedup vs baseline: 1.4485x; 1.4485x over previous
//
#include <hip/hip_runtime.h>

// Problem constants (fixed by setup_inputs)
#define B_    8
#define C_    256
#define H_    100
#define W_    152
#define HW_   (H_ * W_)      // 15200
#define K_    128
#define PH_   7
#define PW_   7
#define GH_   14
#define GW_   14
#define NSAMP 196            // GH_*GW_
#define NROI  (B_ * K_)      // 1024
#define OPB   (C_ * PH_ * PW_)  // 12544 outputs per ROI
#define SOUT_STRIDE 260      // 49 x 260 fp32 staging, 16B-aligned rows

// ---------------------------------------------------------------------------
// Kernel 1: NCHW -> NHWC transpose of feat into workspace.
// Per batch: [256][15200] -> [15200][256]. 64x64 LDS tiles, coalesced both ways.
// ---------------------------------------------------------------------------
#define PTILES 238           // ceil(15200/64)
__global__ __launch_bounds__(256) void nchw_to_nhwc(
    const float* __restrict__ in, float* __restrict__ out)
{
    __shared__ float tile[64][65];

    int bid = blockIdx.x;                 // b*4*PTILES + ct*PTILES + pt
    const int pt = bid % PTILES;  bid /= PTILES;
    const int ct = bid & 3;       bid >>= 2;
    const int b  = bid;
    const int c0 = ct * 64;
    const int p0 = pt * 64;

    const int tx = threadIdx.x & 63;
    const int ty = threadIdx.x >> 6;      // 0..3

    const float* ip = in + ((size_t)b * C_ + c0) * HW_ + p0;
    if (p0 + tx < HW_) {
        for (int r = ty; r < 64; r += 4)
            tile[r][tx] = ip[(size_t)r * HW_ + tx];
    }
    __syncthreads();

    float* op = out + ((size_t)b * HW_ + p0) * C_ + c0;
    for (int r = ty; r < 64; r += 4) {
        if (p0 + r < HW_)
            op[(size_t)r * C_ + tx] = tile[tx][r];
    }
}

// ---------------------------------------------------------------------------
// Kernel 2: ROI gather from NHWC. One 1024-thread block (16 waves) per ROI.
// Wave w handles bins w, w+16, w+32, (w+48). Lane l covers channels 4l..4l+3
// via one float4 load per tap -> fully coalesced 1KB wave-loads.
// Output staged in LDS, stored coalesced.
// ---------------------------------------------------------------------------
__global__ __launch_bounds__(1024) void roi_gather_nhwc(
    const float* __restrict__ nhwc,
    const float* __restrict__ rois,
    const int*   __restrict__ stride_p,
    float*       __restrict__ out)
{
    __shared__ int   s_o[NSAMP][4];
    __shared__ float s_w[NSAMP][4];
    __shared__ __align__(16) float s_out[PH_ * PW_][SOUT_STRIDE];

    const int n = blockIdx.x;             // ROI 0..1023
    const int b = n / K_;
    const int t = threadIdx.x;

    // ---- per-ROI sample descriptors (threads 0..195) ----
    if (t < NSAMP) {
        const float scale = 1.0f / (float)(*stride_p);
        const float* box = rois + n * 4;
        const float x1 = box[0], y1 = box[1], x2 = box[2], y2 = box[3];
        const float start_w = x1 * scale - 0.5f;
        const float start_h = y1 * scale - 0.5f;
        const float bin_w = (x2 - x1) * scale * (1.0f / PW_);
        const float bin_h = (y2 - y1) * scale * (1.0f / PH_);

        const int gh = t / GW_;
        const int gw = t - gh * GW_;
        const float y = start_h + ((float)gh + 0.5f) * 0.5f * bin_h;
        const float x = start_w + ((float)gw + 0.5f) * 0.5f * bin_w;

        const bool valid = (y >= -1.0f) && (y <= (float)H_) &&
                           (x >= -1.0f) && (x <= (float)W_);

        float yc = fminf(fmaxf(y, 0.0f), (float)(H_ - 1));
        float xc = fminf(fmaxf(x, 0.0f), (float)(W_ - 1));
        const float y0f = floorf(yc);
        const float x0f = floorf(xc);
        const float ly = yc - y0f, lx = xc - x0f;
        const float hy = 1.0f - ly, hx = 1.0f - lx;
        const int y0 = (int)y0f;
        const int x0 = (int)x0f;
        const int y1i = min(y0 + 1, H_ - 1);
        const int x1i = min(x0 + 1, W_ - 1);

        const float m = valid ? 0.25f : 0.0f;   // fold the 2x2 sample mean in

        s_o[t][0] = (y0  * W_ + x0 ) * C_;
        s_o[t][1] = (y0  * W_ + x1i) * C_;
        s_o[t][2] = (y1i * W_ + x0 ) * C_;
        s_o[t][3] = (y1i * W_ + x1i) * C_;
        s_w[t][0] = hy * hx * m;
        s_w[t][1] = hy * lx * m;
        s_w[t][2] = ly * hx * m;
        s_w[t][3] = ly * lx * m;
    }
    __syncthreads();

    const int wave = t >> 6;
    const int lane = t & 63;
    const float* fb = nhwc + (size_t)b * HW_ * C_;

    for (int bin = wave; bin < PH_ * PW_; bin += 16) {
        const int ph = bin / 7;
        const int pw = bin - ph * 7;
        float ax = 0.f, ay = 0.f, az = 0.f, aw = 0.f;
        #pragma unroll
        for (int sy = 0; sy < 2; ++sy) {
            #pragma unroll
            for (int sx = 0; sx < 2; ++sx) {
                const int si = (ph * 2 + sy) * GW_ + (pw * 2 + sx);
                #pragma unroll
                for (int j = 0; j < 4; ++j) {
                    const float w = s_w[si][j];
                    const float4 v = *reinterpret_cast<const float4*>(
                        fb + s_o[si][j] + (lane << 2));
                    ax = fmaf(w, v.x, ax);
                    ay = fmaf(w, v.y, ay);
                    az = fmaf(w, v.z, az);
                    aw = fmaf(w, v.w, aw);
                }
            }
        }
        *reinterpret_cast<float4*>(&s_out[bin][lane << 2]) =
            make_float4(ax, ay, az, aw);
    }
    __syncthreads();

    // coalesced store: out[n][c][bin], bin fastest
    float* ob = out + (size_t)n * OPB;
    for (int f = t; f < OPB; f += 1024) {
        const int c   = f / 49;
        const int bin = f - c * 49;
        ob[f] = s_out[bin][c];
    }
}

// ---------------------------------------------------------------------------
// Fallback (round-1 kernel) if workspace is too small for the NHWC copy.
// ---------------------------------------------------------------------------
#define CSPLIT 4
#define CPB   (C_ / CSPLIT)
#define ELEMS (CPB * PH_ * PW_)

__global__ __launch_bounds__(256) void roi_align_fallback(
    const float* __restrict__ feat,
    const float* __restrict__ rois,
    const int*   __restrict__ stride_p,
    float*       __restrict__ out)
{
    __shared__ int   s_off[NSAMP][4];
    __shared__ float s_w[NSAMP][4];

    const int blk   = blockIdx.x;
    const int n     = blk >> 2;
    const int cbase = (blk & 3) * CPB;
    const int b     = n / K_;
    const int t = threadIdx.x;

    if (t < NSAMP) {
        const float scale = 1.0f / (float)(*stride_p);
        const float* box = rois + n * 4;
        const float x1 = box[0], y1 = box[1], x2 = box[2], y2 = box[3];
        const float start_w = x1 * scale - 0.5f;
        const float start_h = y1 * scale - 0.5f;
        const float bin_w = (x2 - x1) * scale * (1.0f / PW_);
        const float bin_h = (y2 - y1) * scale * (1.0f / PH_);
        const int gh = t / GW_;
        const int gw = t - gh * GW_;
        const float y = start_h + ((float)gh + 0.5f) * 0.5f * bin_h;
        const float x = start_w + ((float)gw + 0.5f) * 0.5f * bin_w;
        const bool valid = (y >= -1.0f) && (y <= (float)H_) &&
                           (x >= -1.0f) && (x <= (float)W_);
        float yc = fminf(fmaxf(y, 0.0f), (float)(H_ - 1));
        float xc = fminf(fmaxf(x, 0.0f), (float)(W_ - 1));
        const float y0f = floorf(yc);
        const float x0f = floorf(xc);
        const float ly = yc - y0f, lx = xc - x0f;
        const float hy = 1.0f - ly, hx = 1.0f - lx;
        const int y0 = (int)y0f;
        const int x0 = (int)x0f;
        const int y1i = min(y0 + 1, H_ - 1);
        const int x1i = min(x0 + 1, W_ - 1);
        const float m = valid ? 0.25f : 0.0f;
        s_off[t][0] = y0  * W_ + x0;
        s_off[t][1] = y0  * W_ + x1i;
        s_off[t][2] = y1i * W_ + x0;
        s_off[t][3] = y1i * W_ + x1i;
        s_w[t][0] = hy * hx * m;
        s_w[t][1] = hy * lx * m;
        s_w[t][2] = ly * hx * m;
        s_w[t][3] = ly * lx * m;
    }
    __syncthreads();

    const float* fbp = feat + (size_t)b * C_ * HW_;
    float*       ob  = out  + ((size_t)n * C_ + cbase) * (PH_ * PW_);

    for (int e = t; e < ELEMS; e += 256) {
        const int c   = e / 49;
        const int bin = e - c * 49;
        const int ph  = bin / 7;
        const int pw  = bin - ph * 7;
        const float* fp = fbp + (size_t)(cbase + c) * HW_;
        float acc = 0.0f;
        #pragma unroll
        for (int sy = 0; sy < 2; ++sy) {
            #pragma unroll
            for (int sx = 0; sx < 2; ++sx) {
                const int si = (ph * 2 + sy) * GW_ + (pw * 2 + sx);
                acc += s_w[si][0] * fp[s_off[si][0]]
                     + s_w[si][1] * fp[s_off[si][1]]
                     + s_w[si][2] * fp[s_off[si][2]]
                     + s_w[si][3] * fp[s_off[si][3]];
            }
        }
        ob[e] = acc;
    }
}

extern "C" void kernel_launch(void* const* d_in, const int* in_sizes, int n_in,
                              void* d_out, int out_size, void* d_ws, size_t ws_size,
                              hipStream_t stream) {
    (void)in_sizes; (void)n_in; (void)out_size;
    const float* feat     = (const float*)d_in[0];
    const float* rois     = (const float*)d_in[1];
    const int*   stride_p = (const int*)  d_in[2];
    float*       out      = (float*)d_out;

    const size_t need = (size_t)B_ * HW_ * C_ * sizeof(float);  // 124.5 MB
    if (ws_size >= need) {
        float* nhwc = (float*)d_ws;
        nchw_to_nhwc<<<B_ * 4 * PTILES, 256, 0, stream>>>(feat, nhwc);
        roi_gather_nhwc<<<NROI, 1024, 0, stream>>>(nhwc, rois, stride_p, out);
    } else {
        roi_align_fallback<<<NROI * CSPLIT, 256, 0, stream>>>(feat, rois, stride_p, out);
    }
}

// Round 3
// 86.379 us; speedup vs baseline: 1.8999x; 1.3116x over previous
//
#include <hip/hip_runtime.h>

// Problem constants (fixed by setup_inputs)
#define B_    8
#define C_    256
#define H_    100
#define W_    152
#define HW_   15200
#define K_    128
#define PH_   7
#define PW_   7
#define GW_   14
#define NSAMP 196            // 14*14 sample grid
#define NROI  1024
#define OPB   12544          // 256*7*7 outputs per ROI

// ---- bf16 helpers (RNE) ----
__device__ __forceinline__ unsigned int rne_bf16(unsigned int u) {
    return (u + 0x7fffu + ((u >> 16) & 1u)) >> 16;
}
__device__ __forceinline__ unsigned int pack2bf16(float a, float b) {
    const unsigned int ua = __builtin_bit_cast(unsigned int, a);
    const unsigned int ub = __builtin_bit_cast(unsigned int, b);
    return (rne_bf16(ub) << 16) | rne_bf16(ua);
}
__device__ __forceinline__ float bf2f(unsigned short h) {
    const unsigned int u = ((unsigned int)h) << 16;
    return __builtin_bit_cast(float, u);
}

// ---------------------------------------------------------------------------
// Kernel 1: NCHW fp32 -> NHWC bf16.
// Tile = 64 channels x 256 positions. Loads are 1KB-contiguous per wave-load
// (float4/lane along a channel row); LDS holds channel-PAIR dwords so stores
// are dwordx4 (8 consecutive channels) -> 128B contiguous segments.
// ---------------------------------------------------------------------------
#define NPT 60               // ceil(15200/256); last tile has 96 positions
__global__ __launch_bounds__(256) void nchw_to_nhwc_bf16(
    const float* __restrict__ in, unsigned int* __restrict__ out)
{
    __shared__ unsigned int tile[32][260];   // [cpair][pos], 33.3 KB

    int bid = blockIdx.x;
    const int pt = bid % NPT; bid /= NPT;
    const int ct = bid & 3;   bid >>= 2;
    const int b  = bid;
    const int c0 = ct * 64, p0 = pt * 256;
    const int np = (p0 + 256 <= HW_) ? 256 : (HW_ - p0);   // 256 or 96

    const int t    = threadIdx.x;
    const int wave = t >> 6, lane = t & 63;
    const int p    = lane * 4;

    const float* ip = in + ((size_t)b * C_ + c0) * HW_ + p0;
    if (p < np) {
        #pragma unroll
        for (int i = 0; i < 8; ++i) {
            const int cp = wave * 8 + i;      // channel pair 0..31
            const float4 v0 = *reinterpret_cast<const float4*>(ip + (size_t)(2*cp  ) * HW_ + p);
            const float4 v1 = *reinterpret_cast<const float4*>(ip + (size_t)(2*cp+1) * HW_ + p);
            uint4 d;
            d.x = pack2bf16(v0.x, v1.x);
            d.y = pack2bf16(v0.y, v1.y);
            d.z = pack2bf16(v0.z, v1.z);
            d.w = pack2bf16(v0.w, v1.w);
            *reinterpret_cast<uint4*>(&tile[cp][p]) = d;   // 16B aligned, sequential
        }
    }
    __syncthreads();

    // out dword index = (b*HW + p)*128 + c/2
    unsigned int* op = out + ((size_t)b * HW_ + p0) * 128 + (c0 >> 1);
    for (int pb = 0; pb < np; pb += 32) {          // np is a multiple of 32
        const int pp = pb + (t >> 3);
        const int cp = (t & 7) * 4;                // 4 dwords = 8 channels
        uint4 d;
        d.x = tile[cp + 0][pp];
        d.y = tile[cp + 1][pp];
        d.z = tile[cp + 2][pp];
        d.w = tile[cp + 3][pp];
        *reinterpret_cast<uint4*>(op + (size_t)pp * 128 + cp) = d;
    }
}

// ---------------------------------------------------------------------------
// Kernel 2: ROI gather from NHWC bf16. One 1024-thread block per ROI.
// XCD-swizzled so each XCD handles exactly one batch (7.8MB plane -> L2).
// Lane l covers channels 4l..4l+3 via one ushort4 (8B) load per tap ->
// each tap is a single 512B fully-coalesced wave-load.
// ---------------------------------------------------------------------------
__global__ __launch_bounds__(1024) void roi_gather_nhwc_bf16(
    const unsigned short* __restrict__ nhwc,
    const float* __restrict__ rois,
    const int*   __restrict__ stride_p,
    float*       __restrict__ out)
{
    __shared__ int   s_o[NSAMP][4];
    __shared__ float s_w[NSAMP][4];
    __shared__ float s_out[OPB];               // flat [c*49 + bin], 50.2 KB

    const int bid = blockIdx.x;
    const int n = (bid & 7) * K_ + (bid >> 3); // batch == bid&7 per XCD
    const int b = bid & 7;
    const int t = threadIdx.x;

    if (t < NSAMP) {
        const float scale = 1.0f / (float)(*stride_p);
        const float* box = rois + n * 4;
        const float x1 = box[0], y1 = box[1], x2 = box[2], y2 = box[3];
        const float start_w = x1 * scale - 0.5f;
        const float start_h = y1 * scale - 0.5f;
        const float bin_w = (x2 - x1) * scale * (1.0f / PW_);
        const float bin_h = (y2 - y1) * scale * (1.0f / PH_);

        const int gh = t / GW_;
        const int gw = t - gh * GW_;
        const float y = start_h + ((float)gh + 0.5f) * 0.5f * bin_h;
        const float x = start_w + ((float)gw + 0.5f) * 0.5f * bin_w;

        const bool valid = (y >= -1.0f) && (y <= (float)H_) &&
                           (x >= -1.0f) && (x <= (float)W_);

        float yc = fminf(fmaxf(y, 0.0f), (float)(H_ - 1));
        float xc = fminf(fmaxf(x, 0.0f), (float)(W_ - 1));
        const float y0f = floorf(yc);
        const float x0f = floorf(xc);
        const float ly = yc - y0f, lx = xc - x0f;
        const float hy = 1.0f - ly, hx = 1.0f - lx;
        const int y0 = (int)y0f;
        const int x0 = (int)x0f;
        const int y1i = min(y0 + 1, H_ - 1);
        const int x1i = min(x0 + 1, W_ - 1);

        const float m = valid ? 0.25f : 0.0f;  // fold 2x2 sample mean in

        s_o[t][0] = (y0  * W_ + x0 ) * C_;     // bf16-element offsets
        s_o[t][1] = (y0  * W_ + x1i) * C_;
        s_o[t][2] = (y1i * W_ + x0 ) * C_;
        s_o[t][3] = (y1i * W_ + x1i) * C_;
        s_w[t][0] = hy * hx * m;
        s_w[t][1] = hy * lx * m;
        s_w[t][2] = ly * hx * m;
        s_w[t][3] = ly * lx * m;
    }
    __syncthreads();

    const int wave = t >> 6, lane = t & 63;
    const unsigned short* fb = nhwc + (size_t)b * HW_ * C_;

    for (int bin = wave; bin < PH_ * PW_; bin += 16) {
        const int ph = bin / 7;
        const int pw = bin - ph * 7;
        float a0 = 0.f, a1 = 0.f, a2 = 0.f, a3 = 0.f;
        #pragma unroll
        for (int sy = 0; sy < 2; ++sy) {
            #pragma unroll
            for (int sx = 0; sx < 2; ++sx) {
                const int si = (ph * 2 + sy) * GW_ + (pw * 2 + sx);
                #pragma unroll
                for (int j = 0; j < 4; ++j) {
                    const float w = s_w[si][j];
                    const ushort4 v = *reinterpret_cast<const ushort4*>(
                        fb + s_o[si][j] + (lane << 2));
                    a0 = fmaf(w, bf2f(v.x), a0);
                    a1 = fmaf(w, bf2f(v.y), a1);
                    a2 = fmaf(w, bf2f(v.z), a2);
                    a3 = fmaf(w, bf2f(v.w), a3);
                }
            }
        }
        const int c = lane << 2;
        s_out[(c + 0) * 49 + bin] = a0;
        s_out[(c + 1) * 49 + bin] = a1;
        s_out[(c + 2) * 49 + bin] = a2;
        s_out[(c + 3) * 49 + bin] = a3;
    }
    __syncthreads();

    // fully sequential LDS reads + coalesced stores
    float* ob = out + (size_t)n * OPB;
    for (int f = t; f < OPB; f += 1024) ob[f] = s_out[f];
}

// ---------------------------------------------------------------------------
// Fallback (round-1 kernel, fp32 NCHW direct) if workspace too small.
// ---------------------------------------------------------------------------
#define CSPLIT 4
#define CPB   (C_ / CSPLIT)
#define ELEMS (CPB * PH_ * PW_)

__global__ __launch_bounds__(256) void roi_align_fallback(
    const float* __restrict__ feat,
    const float* __restrict__ rois,
    const int*   __restrict__ stride_p,
    float*       __restrict__ out)
{
    __shared__ int   s_off[NSAMP][4];
    __shared__ float s_w[NSAMP][4];

    const int blk   = blockIdx.x;
    const int n     = blk >> 2;
    const int cbase = (blk & 3) * CPB;
    const int b     = n / K_;
    const int t = threadIdx.x;

    if (t < NSAMP) {
        const float scale = 1.0f / (float)(*stride_p);
        const float* box = rois + n * 4;
        const float x1 = box[0], y1 = box[1], x2 = box[2], y2 = box[3];
        const float start_w = x1 * scale - 0.5f;
        const float start_h = y1 * scale - 0.5f;
        const float bin_w = (x2 - x1) * scale * (1.0f / PW_);
        const float bin_h = (y2 - y1) * scale * (1.0f / PH_);
        const int gh = t / GW_;
        const int gw = t - gh * GW_;
        const float y = start_h + ((float)gh + 0.5f) * 0.5f * bin_h;
        const float x = start_w + ((float)gw + 0.5f) * 0.5f * bin_w;
        const bool valid = (y >= -1.0f) && (y <= (float)H_) &&
                           (x >= -1.0f) && (x <= (float)W_);
        float yc = fminf(fmaxf(y, 0.0f), (float)(H_ - 1));
        float xc = fminf(fmaxf(x, 0.0f), (float)(W_ - 1));
        const float y0f = floorf(yc);
        const float x0f = floorf(xc);
        const float ly = yc - y0f, lx = xc - x0f;
        const float hy = 1.0f - ly, hx = 1.0f - lx;
        const int y0 = (int)y0f;
        const int x0 = (int)x0f;
        const int y1i = min(y0 + 1, H_ - 1);
        const int x1i = min(x0 + 1, W_ - 1);
        const float m = valid ? 0.25f : 0.0f;
        s_off[t][0] = y0  * W_ + x0;
        s_off[t][1] = y0  * W_ + x1i;
        s_off[t][2] = y1i * W_ + x0;
        s_off[t][3] = y1i * W_ + x1i;
        s_w[t][0] = hy * hx * m;
        s_w[t][1] = hy * lx * m;
        s_w[t][2] = ly * hx * m;
        s_w[t][3] = ly * lx * m;
    }
    __syncthreads();

    const float* fbp = feat + (size_t)b * C_ * HW_;
    float*       ob  = out  + ((size_t)n * C_ + cbase) * (PH_ * PW_);

    for (int e = t; e < ELEMS; e += 256) {
        const int c   = e / 49;
        const int bin = e - c * 49;
        const int ph  = bin / 7;
        const int pw  = bin - ph * 7;
        const float* fp = fbp + (size_t)(cbase + c) * HW_;
        float acc = 0.0f;
        #pragma unroll
        for (int sy = 0; sy < 2; ++sy) {
            #pragma unroll
            for (int sx = 0; sx < 2; ++sx) {
                const int si = (ph * 2 + sy) * GW_ + (pw * 2 + sx);
                acc += s_w[si][0] * fp[s_off[si][0]]
                     + s_w[si][1] * fp[s_off[si][1]]
                     + s_w[si][2] * fp[s_off[si][2]]
                     + s_w[si][3] * fp[s_off[si][3]];
            }
        }
        ob[e] = acc;
    }
}

extern "C" void kernel_launch(void* const* d_in, const int* in_sizes, int n_in,
                              void* d_out, int out_size, void* d_ws, size_t ws_size,
                              hipStream_t stream) {
    (void)in_sizes; (void)n_in; (void)out_size;
    const float* feat     = (const float*)d_in[0];
    const float* rois     = (const float*)d_in[1];
    const int*   stride_p = (const int*)  d_in[2];
    float*       out      = (float*)d_out;

    const size_t need = (size_t)B_ * HW_ * C_ * 2;   // 62.3 MB bf16 NHWC
    if (ws_size >= need) {
        nchw_to_nhwc_bf16<<<B_ * 4 * NPT, 256, 0, stream>>>(
            feat, (unsigned int*)d_ws);
        roi_gather_nhwc_bf16<<<NROI, 1024, 0, stream>>>(
            (const unsigned short*)d_ws, rois, stride_p, out);
    } else {
        roi_align_fallback<<<NROI * CSPLIT, 256, 0, stream>>>(
            feat, rois, stride_p, out);
    }
}

// Round 5
// 68.894 us; speedup vs baseline: 2.3820x; 1.2538x over previous
//
#include <hip/hip_runtime.h>

// Problem constants (fixed by setup_inputs)
#define B_    8
#define C_    256
#define H_    100
#define W_    152
#define HW_   15200
#define K_    128
#define PH_   7
#define PW_   7
#define GW_   14
#define NSAMP 196            // 14*14 sample grid
#define NROI  1024
#define OPB   12544          // 256*7*7 outputs per ROI
#define HOPB  6272           // half-channel outputs per ROI

typedef float  f4v  __attribute__((ext_vector_type(4)));

// ---- bf16 helpers (RNE) ----
__device__ __forceinline__ unsigned int rne_bf16(unsigned int u) {
    return (u + 0x7fffu + ((u >> 16) & 1u)) >> 16;
}
__device__ __forceinline__ unsigned int pack2bf16(float a, float b) {
    const unsigned int ua = __builtin_bit_cast(unsigned int, a);
    const unsigned int ub = __builtin_bit_cast(unsigned int, b);
    return (rne_bf16(ub) << 16) | rne_bf16(ua);
}

// ---------------------------------------------------------------------------
// Kernel 1: NCHW fp32 -> [B][half][HW][128] bf16.
// Tile = 64 channels x 256 positions. Non-temporal 16B loads (feat is
// read-once). LDS holds channel-pair dwords; tile[cp] == channel pair cp of
// this block's 64 channels, stored at dword (ct&1)*32 + cp of the half-row.
// ---------------------------------------------------------------------------
#define NPT 60               // ceil(15200/256); last tile has 96 positions
__global__ __launch_bounds__(256) void nchw_to_nhwc_bf16(
    const float* __restrict__ in, unsigned int* __restrict__ out)
{
    __shared__ unsigned int tile[32][260];   // [cpair][pos], 33.3 KB

    int bid = blockIdx.x;
    const int pt = bid % NPT; bid /= NPT;
    const int ct = bid & 3;   bid >>= 2;
    const int b  = bid;
    const int c0 = ct * 64, p0 = pt * 256;
    const int np = (p0 + 256 <= HW_) ? 256 : (HW_ - p0);   // 256 or 96

    const int t    = threadIdx.x;
    const int wave = t >> 6, lane = t & 63;
    const int p    = lane * 4;

    const float* ip = in + ((size_t)b * C_ + c0) * HW_ + p0;
    if (p < np) {
        #pragma unroll
        for (int i = 0; i < 8; ++i) {
            const int cp = wave * 8 + i;      // channel pair 0..31
            const f4v v0 = __builtin_nontemporal_load(
                reinterpret_cast<const f4v*>(ip + (size_t)(2*cp  ) * HW_ + p));
            const f4v v1 = __builtin_nontemporal_load(
                reinterpret_cast<const f4v*>(ip + (size_t)(2*cp+1) * HW_ + p));
            uint4 d;
            d.x = pack2bf16(v0[0], v1[0]);
            d.y = pack2bf16(v0[1], v1[1]);
            d.z = pack2bf16(v0[2], v1[2]);
            d.w = pack2bf16(v0[3], v1[3]);
            *reinterpret_cast<uint4*>(&tile[cp][p]) = d;
        }
    }
    __syncthreads();

    // dest dword index = ((b*2 + half)*HW + p)*64 + (ct&1)*32 + cp
    const int half = ct >> 1;
    unsigned int* op = out + ((size_t)(b * 2 + half) * HW_ + p0) * 64
                           + (ct & 1) * 32;
    for (int pb = 0; pb < np; pb += 32) {          // np is a multiple of 32
        const int pp = pb + (t >> 3);
        const int cp = (t & 7) * 4;                // 4 dwords = 8 channels
        uint4 d;
        d.x = tile[cp + 0][pp];
        d.y = tile[cp + 1][pp];
        d.z = tile[cp + 2][pp];
        d.w = tile[cp + 3][pp];
        *reinterpret_cast<uint4*>(op + (size_t)pp * 64 + cp) = d;
    }
}

// ---------------------------------------------------------------------------
// Kernel 2: ROI gather from [B][half][HW][128] bf16.
// 2048 blocks x 512 threads. Phase (= channel half) is the slowest-moving
// index so each scheduling generation works on a 3.9MB/XCD working set
// (fits per-XCD L2). batch == bid&7 keeps each batch on one XCD.
// Lane covers channels 2l,2l+1 via one dword -> 256B coalesced wave-loads.
// ---------------------------------------------------------------------------
__global__ __launch_bounds__(512) void roi_gather_half(
    const unsigned int* __restrict__ nhwc,   // dword view
    const float* __restrict__ rois,
    const int*   __restrict__ stride_p,
    float*       __restrict__ out)
{
    __shared__ int   s_o[NSAMP][4];
    __shared__ float s_w[NSAMP][4];
    __shared__ float s_out[HOPB];            // [cLocal*49 + bin], 25 KB

    const int bid  = blockIdx.x;
    const int half = bid >> 10;
    const int b    = bid & 7;
    const int n    = b * K_ + ((bid >> 3) & 127);
    const int t    = threadIdx.x;

    if (t < NSAMP) {
        const float scale = 1.0f / (float)(*stride_p);
        const float* box = rois + n * 4;
        const float x1 = box[0], y1 = box[1], x2 = box[2], y2 = box[3];
        const float start_w = x1 * scale - 0.5f;
        const float start_h = y1 * scale - 0.5f;
        const float bin_w = (x2 - x1) * scale * (1.0f / PW_);
        const float bin_h = (y2 - y1) * scale * (1.0f / PH_);

        const int gh = t / GW_;
        const int gw = t - gh * GW_;
        const float y = start_h + ((float)gh + 0.5f) * 0.5f * bin_h;
        const float x = start_w + ((float)gw + 0.5f) * 0.5f * bin_w;

        const bool valid = (y >= -1.0f) && (y <= (float)H_) &&
                           (x >= -1.0f) && (x <= (float)W_);

        float yc = fminf(fmaxf(y, 0.0f), (float)(H_ - 1));
        float xc = fminf(fmaxf(x, 0.0f), (float)(W_ - 1));
        const float y0f = floorf(yc);
        const float x0f = floorf(xc);
        const float ly = yc - y0f, lx = xc - x0f;
        const float hy = 1.0f - ly, hx = 1.0f - lx;
        const int y0 = (int)y0f;
        const int x0 = (int)x0f;
        const int y1i = min(y0 + 1, H_ - 1);
        const int x1i = min(x0 + 1, W_ - 1);

        const float m = valid ? 0.25f : 0.0f;  // fold 2x2 sample mean in

        s_o[t][0] = (y0  * W_ + x0 ) * 64;     // dword offsets in half-plane
        s_o[t][1] = (y0  * W_ + x1i) * 64;
        s_o[t][2] = (y1i * W_ + x0 ) * 64;
        s_o[t][3] = (y1i * W_ + x1i) * 64;
        s_w[t][0] = hy * hx * m;
        s_w[t][1] = hy * lx * m;
        s_w[t][2] = ly * hx * m;
        s_w[t][3] = ly * lx * m;
    }
    __syncthreads();

    const int wave = t >> 6, lane = t & 63;
    const unsigned int* fb = nhwc + (size_t)(b * 2 + half) * HW_ * 64;

    for (int bin = wave; bin < PH_ * PW_; bin += 8) {
        const int ph = bin / 7;
        const int pw = bin - ph * 7;
        float a0 = 0.f, a1 = 0.f;
        #pragma unroll
        for (int sy = 0; sy < 2; ++sy) {
            #pragma unroll
            for (int sx = 0; sx < 2; ++sx) {
                const int si = (ph * 2 + sy) * GW_ + (pw * 2 + sx);
                #pragma unroll
                for (int j = 0; j < 4; ++j) {
                    const float w = s_w[si][j];
                    const unsigned int v = fb[s_o[si][j] + lane];
                    a0 = fmaf(w, __builtin_bit_cast(float, v << 16), a0);
                    a1 = fmaf(w, __builtin_bit_cast(float, v & 0xffff0000u), a1);
                }
            }
        }
        const int c = lane << 1;
        s_out[(c + 0) * 49 + bin] = a0;
        s_out[(c + 1) * 49 + bin] = a1;
    }
    __syncthreads();

    // sequential LDS reads + coalesced non-temporal stores (out never re-read)
    float* ob = out + (size_t)n * OPB + half * HOPB;
    for (int f = t; f < HOPB; f += 512)
        __builtin_nontemporal_store(s_out[f], ob + f);
}

// ---------------------------------------------------------------------------
// Fallback (round-1 kernel, fp32 NCHW direct) if workspace too small.
// ---------------------------------------------------------------------------
#define CSPLIT 4
#define CPB   (C_ / CSPLIT)
#define ELEMS (CPB * PH_ * PW_)

__global__ __launch_bounds__(256) void roi_align_fallback(
    const float* __restrict__ feat,
    const float* __restrict__ rois,
    const int*   __restrict__ stride_p,
    float*       __restrict__ out)
{
    __shared__ int   s_off[NSAMP][4];
    __shared__ float s_w[NSAMP][4];

    const int blk   = blockIdx.x;
    const int n     = blk >> 2;
    const int cbase = (blk & 3) * CPB;
    const int b     = n / K_;
    const int t = threadIdx.x;

    if (t < NSAMP) {
        const float scale = 1.0f / (float)(*stride_p);
        const float* box = rois + n * 4;
        const float x1 = box[0], y1 = box[1], x2 = box[2], y2 = box[3];
        const float start_w = x1 * scale - 0.5f;
        const float start_h = y1 * scale - 0.5f;
        const float bin_w = (x2 - x1) * scale * (1.0f / PW_);
        const float bin_h = (y2 - y1) * scale * (1.0f / PH_);
        const int gh = t / GW_;
        const int gw = t - gh * GW_;
        const float y = start_h + ((float)gh + 0.5f) * 0.5f * bin_h;
        const float x = start_w + ((float)gw + 0.5f) * 0.5f * bin_w;
        const bool valid = (y >= -1.0f) && (y <= (float)H_) &&
                           (x >= -1.0f) && (x <= (float)W_);
        float yc = fminf(fmaxf(y, 0.0f), (float)(H_ - 1));
        float xc = fminf(fmaxf(x, 0.0f), (float)(W_ - 1));
        const float y0f = floorf(yc);
        const float x0f = floorf(xc);
        const float ly = yc - y0f, lx = xc - x0f;
        const float hy = 1.0f - ly, hx = 1.0f - lx;
        const int y0 = (int)y0f;
        const int x0 = (int)x0f;
        const int y1i = min(y0 + 1, H_ - 1);
        const int x1i = min(x0 + 1, W_ - 1);
        const float m = valid ? 0.25f : 0.0f;
        s_off[t][0] = y0  * W_ + x0;
        s_off[t][1] = y0  * W_ + x1i;
        s_off[t][2] = y1i * W_ + x0;
        s_off[t][3] = y1i * W_ + x1i;
        s_w[t][0] = hy * hx * m;
        s_w[t][1] = hy * lx * m;
        s_w[t][2] = ly * hx * m;
        s_w[t][3] = ly * lx * m;
    }
    __syncthreads();

    const float* fbp = feat + (size_t)b * C_ * HW_;
    float*       ob  = out  + ((size_t)n * C_ + cbase) * (PH_ * PW_);

    for (int e = t; e < ELEMS; e += 256) {
        const int c   = e / 49;
        const int bin = e - c * 49;
        const int ph  = bin / 7;
        const int pw  = bin - ph * 7;
        const float* fp = fbp + (size_t)(cbase + c) * HW_;
        float acc = 0.0f;
        #pragma unroll
        for (int sy = 0; sy < 2; ++sy) {
            #pragma unroll
            for (int sx = 0; sx < 2; ++sx) {
                const int si = (ph * 2 + sy) * GW_ + (pw * 2 + sx);
                acc += s_w[si][0] * fp[s_off[si][0]]
                     + s_w[si][1] * fp[s_off[si][1]]
                     + s_w[si][2] * fp[s_off[si][2]]
                     + s_w[si][3] * fp[s_off[si][3]];
            }
        }
        ob[e] = acc;
    }
}

extern "C" void kernel_launch(void* const* d_in, const int* in_sizes, int n_in,
                              void* d_out, int out_size, void* d_ws, size_t ws_size,
                              hipStream_t stream) {
    (void)in_sizes; (void)n_in; (void)out_size;
    const float* feat     = (const float*)d_in[0];
    const float* rois     = (const float*)d_in[1];
    const int*   stride_p = (const int*)  d_in[2];
    float*       out      = (float*)d_out;

    const size_t need = (size_t)B_ * HW_ * C_ * 2;   // 62.3 MB bf16
    if (ws_size >= need) {
        nchw_to_nhwc_bf16<<<B_ * 4 * NPT, 256, 0, stream>>>(
            feat, (unsigned int*)d_ws);
        roi_gather_half<<<2 * NROI, 512, 0, stream>>>(
            (const unsigned int*)d_ws, rois, stride_p, out);
    } else {
        roi_align_fallback<<<NROI * CSPLIT, 256, 0, stream>>>(
            feat, rois, stride_p, out);
    }
}